// Round 1
// baseline (1969.533 us; speedup 1.0000x reference)
//
#include <hip/hip_runtime.h>

#define HID    51
#define G4     204    // 4*HID
#define EMB    7
#define VOCAB  282
#define TT     1024
#define BB     256

__device__ __forceinline__ float sigf(float x) {
    return 1.0f / (1.0f + __expf(-x));
}
__device__ __forceinline__ float tanh_fast(float x) {
    // tanh(x) = 1 - 2/(exp(2x)+1); saturates correctly for large |x|
    return 1.0f - 2.0f / (__expf(2.0f * x) + 1.0f);
}

// ---------- Kernel A: eproj[v][j] = b1[j] + sum_e embed[v][e]*w_ih1[j][e] ----------
__global__ void eproj_kernel(const float* __restrict__ embed,
                             const float* __restrict__ w_ih1,
                             const float* __restrict__ b1,
                             float* __restrict__ eproj) {
    int idx = blockIdx.x * blockDim.x + threadIdx.x;
    if (idx >= VOCAB * G4) return;
    int v = idx / G4;
    int j = idx - v * G4;
    float acc = b1[j];
    #pragma unroll
    for (int e = 0; e < EMB; e++)
        acc += embed[v * EMB + e] * w_ih1[j * EMB + e];
    eproj[idx] = acc;
}

// ---------- Kernel B: recurrent LSTM, one block per batch item ----------
__launch_bounds__(256, 1)
__global__ void lstm_kernel(const int* __restrict__ input,
                            const float* __restrict__ eproj,
                            const float* __restrict__ w_hh1,
                            const float* __restrict__ w_ih2,
                            const float* __restrict__ w_hh2,
                            const float* __restrict__ b2,
                            float* __restrict__ out) {
    __shared__ float h1s[52];
    __shared__ float h2s[52];
    __shared__ float g1s[G4];
    __shared__ float g2s[G4];
    __shared__ int   toks[TT];

    const int j = threadIdx.x;
    const int b = blockIdx.x;

    // stage tokens for this batch item (coalesced)
    for (int i = j; i < TT; i += 256) toks[i] = input[b * TT + i];
    if (j < 52) { h1s[j] = 0.0f; h2s[j] = 0.0f; }

    // per-gate weights in registers (fully unrolled -> static indices -> VGPRs)
    float wh1[HID], wi2[HID], wh2[HID];
    float b2j = 0.0f;
    if (j < G4) {
        #pragma unroll
        for (int k = 0; k < HID; k++) {
            wh1[k] = w_hh1[j * HID + k];
            wi2[k] = w_ih2[j * HID + k];
            wh2[k] = w_hh2[j * HID + k];
        }
        b2j = b2[j];
    }
    float c1 = 0.0f, c2 = 0.0f;
    __syncthreads();

    // prefetch eproj row for t=0
    float gpref = (j < G4) ? eproj[toks[0] * G4 + j] : 0.0f;

    for (int t = 0; t < TT; t++) {
        float g1in = gpref;
        if (j < G4 && (t + 1) < TT)      // prefetch next step's row (hidden under compute)
            gpref = eproj[toks[t + 1] * G4 + j];

        // Phase 1: layer-1 gates (204 threads, 51 FMA each; h1s reads broadcast)
        if (j < G4) {
            float acc = g1in;
            #pragma unroll
            for (int k = 0; k < HID; k++) acc += wh1[k] * h1s[k];
            g1s[j] = acc;
        }
        __syncthreads();

        // Phase 2: layer-1 cell update (51 threads)
        if (j < HID) {
            float ig = sigf(g1s[j]);
            float fg = sigf(g1s[j + HID]);
            float gg = tanh_fast(g1s[j + 2 * HID]);
            float og = sigf(g1s[j + 3 * HID]);
            c1 = fg * c1 + ig * gg;
            h1s[j] = og * tanh_fast(c1);
        }
        __syncthreads();

        // Phase 3: layer-2 gates (204 threads, 102 FMA each)
        if (j < G4) {
            float acc = b2j;
            #pragma unroll
            for (int k = 0; k < HID; k++) acc += wi2[k] * h1s[k];
            #pragma unroll
            for (int k = 0; k < HID; k++) acc += wh2[k] * h2s[k];
            g2s[j] = acc;
        }
        __syncthreads();

        // Phase 4: layer-2 cell update + store h2 into d_out row (first 51 slots)
        if (j < HID) {
            float ig = sigf(g2s[j]);
            float fg = sigf(g2s[j + HID]);
            float gg = tanh_fast(g2s[j + 2 * HID]);
            float og = sigf(g2s[j + 3 * HID]);
            c2 = fg * c2 + ig * gg;
            float h2 = og * tanh_fast(c2);
            h2s[j] = h2;
            out[((size_t)b * TT + t) * VOCAB + j] = h2;
        }
        __syncthreads();
    }
}

// ---------- Kernel C: logits = h2 @ w_lin.T + b_lin, in-place over d_out ----------
#define CB     320    // 5 waves; threads 282..319 idle in compute
#define CROWS  32

__launch_bounds__(CB, 1)
__global__ void logits_kernel(const float* __restrict__ w_lin,
                              const float* __restrict__ b_lin,
                              float* __restrict__ out) {
    __shared__ float wl[VOCAB * HID];   // 57.5 KB
    __shared__ float bl[VOCAB];
    __shared__ float h2r[CROWS][52];

    const int tid = threadIdx.x;
    const size_t r0 = (size_t)blockIdx.x * CROWS;

    for (int i = tid; i < VOCAB * HID; i += CB) wl[i] = w_lin[i];
    for (int i = tid; i < VOCAB; i += CB)       bl[i] = b_lin[i];
    for (int i = tid; i < CROWS * HID; i += CB) {
        int row = i / HID, k = i - row * HID;
        h2r[row][k] = out[(r0 + row) * VOCAB + k];   // read h2 BEFORE overwrite
    }
    __syncthreads();

    if (tid < VOCAB) {
        float wr[HID];
        #pragma unroll
        for (int k = 0; k < HID; k++) wr[k] = wl[tid * HID + k];
        float bv = bl[tid];
        for (int row = 0; row < CROWS; row++) {
            float acc = bv;
            #pragma unroll
            for (int k = 0; k < HID; k++) acc += wr[k] * h2r[row][k];
            out[(r0 + row) * VOCAB + tid] = acc;
        }
    }
}

extern "C" void kernel_launch(void* const* d_in, const int* in_sizes, int n_in,
                              void* d_out, int out_size, void* d_ws, size_t ws_size,
                              hipStream_t stream) {
    const int*   input = (const int*)  d_in[0];
    // d_in[1] = future (always 0 in setup_inputs)
    const float* embed = (const float*)d_in[2];
    const float* w_ih1 = (const float*)d_in[3];
    const float* w_hh1 = (const float*)d_in[4];
    const float* b1    = (const float*)d_in[5];
    const float* w_ih2 = (const float*)d_in[6];
    const float* w_hh2 = (const float*)d_in[7];
    const float* b2    = (const float*)d_in[8];
    const float* w_lin = (const float*)d_in[9];
    const float* b_lin = (const float*)d_in[10];
    float* out   = (float*)d_out;
    float* eproj = (float*)d_ws;     // 282*204*4 = 230 KB scratch

    const int n1 = VOCAB * G4;
    eproj_kernel<<<(n1 + 255) / 256, 256, 0, stream>>>(embed, w_ih1, b1, eproj);
    lstm_kernel<<<BB, 256, 0, stream>>>(input, eproj, w_hh1, w_ih2, w_hh2, b2, out);
    logits_kernel<<<(BB * TT) / CROWS, CB, 0, stream>>>(w_lin, b_lin, out);
}

// Round 2
// 1622.294 us; speedup vs baseline: 1.2140x; 1.2140x over previous
//
#include <hip/hip_runtime.h>

#define HID    51
#define G4     204    // 4*HID
#define EMB    7
#define VOCAB  282
#define TT     1024
#define BB     256

__device__ __forceinline__ float tanh_fast(float x) {
    return 1.0f - 2.0f / (__expf(2.0f * x) + 1.0f);
}

// ---------- Kernel A: eproj[v][j] = b1[j] + sum_e embed[v][e]*w_ih1[j][e] ----------
__global__ void eproj_kernel(const float* __restrict__ embed,
                             const float* __restrict__ w_ih1,
                             const float* __restrict__ b1,
                             float* __restrict__ eproj) {
    int idx = blockIdx.x * blockDim.x + threadIdx.x;
    if (idx >= VOCAB * G4) return;
    int v = idx / G4;
    int j = idx - v * G4;
    float acc = b1[j];
    #pragma unroll
    for (int e = 0; e < EMB; e++)
        acc += embed[v * EMB + e] * w_ih1[j * EMB + e];
    eproj[idx] = acc;
}

// ---------- Kernel B: recurrent LSTM, layer-pipelined, one block per batch item ----
// Waves 0-3: layer 1 at super-step s computes t=s.
// Waves 4-7: layer 2 at super-step s computes t=s-1.
// Lane mapping within a group: jj = (lane>>2) local elem, q = lane&3 gate type.
// Each lane computes a FULL 51-k dot per gate; i/f/g/o gathered via quad shuffles.
__launch_bounds__(512, 2)
__global__ void lstm_kernel(const int* __restrict__ input,
                            const float* __restrict__ eproj,
                            const float* __restrict__ w_hh1,
                            const float* __restrict__ w_ih2,
                            const float* __restrict__ w_hh2,
                            const float* __restrict__ b2,
                            float* __restrict__ out) {
    __shared__ __align__(16) float h1b[2][52];   // 52*4=208B rows: 13 aligned float4
    __shared__ __align__(16) float h2b[2][52];
    __shared__ int toks[TT];

    const int tid = threadIdx.x;
    const int b   = blockIdx.x;

    for (int i = tid; i < TT; i += 512) toks[i] = input[b * TT + i];
    if (tid < 52) {
        h1b[0][tid] = 0.f; h1b[1][tid] = 0.f;
        h2b[0][tid] = 0.f; h2b[1][tid] = 0.f;
    }

    const bool isL2 = (tid >= 256);
    const int  lt   = isL2 ? (tid - 256) : tid;   // 0..255 within group
    const int  w    = lt >> 6;                    // wave-in-group 0..3
    const int  l    = lt & 63;
    const int  jj   = l >> 2;                     // 0..15
    const int  q    = l & 3;                      // gate type: 0=i 1=f 2=g 3=o
    const int  ne   = (w < 3) ? 13 : 12;          // elems per wave (3*13+12=51)
    const bool al   = (jj < ne);                  // active lane
    const int  j    = 13 * w + jj;                // hidden element index
    const int  gs   = al ? (q * 51 + j) : 0;      // safe gate row

    __syncthreads();   // toks + zeroed h buffers visible

    float wA[51], wB[51];
    float b2g = 0.f;
    if (!isL2) {
        #pragma unroll
        for (int k = 0; k < 51; k++) { wA[k] = w_hh1[gs * 51 + k]; wB[k] = 0.f; }
    } else {
        #pragma unroll
        for (int k = 0; k < 51; k++) { wA[k] = w_ih2[gs * 51 + k]; wB[k] = w_hh2[gs * 51 + k]; }
        b2g = b2[gs];
    }

    float c = 0.f, hb0 = 0.f, hb1 = 0.f;
    float ep_cur = 0.f;
    if (!isL2) ep_cur = eproj[toks[0] * G4 + gs];

    for (int s = 0; s <= TT; ++s) {
        const int rp = (s + 1) & 1;   // parity holding state of step s-1
        const int wp = s & 1;

        float x;
        if (!isL2) {
            // prefetch next step's eproj row (covered by this step's compute)
            const int sn = (s + 1 < TT) ? (s + 1) : 0;
            const float ep_nxt = eproj[toks[sn] * G4 + gs];

            float a0 = 0.f, a1 = 0.f, a2 = 0.f, a3 = 0.f;
            const float4* hp = (const float4*)h1b[rp];
            #pragma unroll
            for (int i = 0; i < 13; i++) {
                float4 hv = hp[i];
                const int k = 4 * i;
                a0 += wA[k] * hv.x;
                if (k + 1 < 51) a1 += wA[k + 1] * hv.y;
                if (k + 2 < 51) a2 += wA[k + 2] * hv.z;
                if (k + 3 < 51) a3 += wA[k + 3] * hv.w;
            }
            x = (a0 + a1) + (a2 + a3) + ep_cur;

            // branch-free unified activation: sigmoid for i/f/o, tanh for g
            const float As = (q == 2) ? 2.f : 1.f;
            const float Bs = (q == 2) ? -1.f : 0.f;
            const float act = As / (1.f + __expf(-As * x)) + Bs;
            // gather quad's 4 activations (all lanes execute: no exec-mask holes)
            const float v0 = act;
            const float v1 = __shfl_xor(act, 1);
            const float v2 = __shfl_xor(act, 2);
            const float v3 = __shfl_xor(v2, 1);
            const float t0 = (q & 1) ? v1 : v0, t1 = (q & 1) ? v0 : v1;
            const float t2 = (q & 1) ? v3 : v2, t3 = (q & 1) ? v2 : v3;
            const float I = (q & 2) ? t2 : t0, F = (q & 2) ? t3 : t1;
            const float G = (q & 2) ? t0 : t2, O = (q & 2) ? t1 : t3;
            const float cn = F * c + I * G;
            const float hn = O * tanh_fast(cn);
            if (s < TT) {
                c = cn;
                if (q == 0 && al) h1b[wp][j] = hn;
            }
            ep_cur = ep_nxt;
        } else {
            const int t = s - 1;
            float a0 = 0.f, a1 = 0.f, a2 = 0.f, a3 = 0.f;
            const float4* hp1 = (const float4*)h1b[rp];   // h1(t)
            const float4* hp2 = (const float4*)h2b[wp];   // h2(t-1)
            #pragma unroll
            for (int i = 0; i < 13; i++) {
                float4 ha = hp1[i];
                float4 hb = hp2[i];
                const int k = 4 * i;
                a0 += wA[k] * ha.x;       a2 += wB[k] * hb.x;
                if (k + 1 < 51) { a1 += wA[k + 1] * ha.y; a3 += wB[k + 1] * hb.y; }
                if (k + 2 < 51) { a0 += wA[k + 2] * ha.z; a2 += wB[k + 2] * hb.z; }
                if (k + 3 < 51) { a1 += wA[k + 3] * ha.w; a3 += wB[k + 3] * hb.w; }
            }
            x = (a0 + a1) + (a2 + a3) + b2g;

            const float As = (q == 2) ? 2.f : 1.f;
            const float Bs = (q == 2) ? -1.f : 0.f;
            const float act = As / (1.f + __expf(-As * x)) + Bs;
            const float v0 = act;
            const float v1 = __shfl_xor(act, 1);
            const float v2 = __shfl_xor(act, 2);
            const float v3 = __shfl_xor(v2, 1);
            const float t0 = (q & 1) ? v1 : v0, t1 = (q & 1) ? v0 : v1;
            const float t2 = (q & 1) ? v3 : v2, t3 = (q & 1) ? v2 : v3;
            const float I = (q & 2) ? t2 : t0, F = (q & 2) ? t3 : t1;
            const float G = (q & 2) ? t0 : t2, O = (q & 2) ? t1 : t3;
            const float cn = F * c + I * G;
            const float hn = O * tanh_fast(cn);
            if (t >= 0) {
                c = cn;
                if (q == 0 && al) h2b[t & 1][j] = hn;
                // register-buffer h2 for the output; burst-store every 8 steps
                const int ph = t & 7;
                if (ph == 2 * q)     hb0 = hn;
                if (ph == 2 * q + 1) hb1 = hn;
                if (ph == 7 && al) {
                    const size_t base = (size_t)b * TT + (t & ~7);
                    out[(base + 2 * q)     * VOCAB + j] = hb0;
                    out[(base + 2 * q + 1) * VOCAB + j] = hb1;
                }
            }
        }
        __syncthreads();
    }
}

// ---------- Kernel C: logits = h2 @ w_lin.T + b_lin, in-place over d_out ----------
#define CB     320
#define CROWS  32

__launch_bounds__(CB, 1)
__global__ void logits_kernel(const float* __restrict__ w_lin,
                              const float* __restrict__ b_lin,
                              float* __restrict__ out) {
    __shared__ float wl[VOCAB * HID];                 // 57.5 KB
    __shared__ float bl[VOCAB];
    __shared__ __align__(16) float h2r[CROWS][52];    // padded rows: 13 float4 each

    const int tid = threadIdx.x;
    const size_t r0 = (size_t)blockIdx.x * CROWS;

    for (int i = tid; i < VOCAB * HID; i += CB) wl[i] = w_lin[i];
    for (int i = tid; i < VOCAB; i += CB)       bl[i] = b_lin[i];
    for (int i = tid; i < CROWS * HID; i += CB) {
        int row = i / HID, k = i - row * HID;
        h2r[row][k] = out[(r0 + row) * VOCAB + k];   // read h2 BEFORE overwrite
    }
    if (tid < CROWS) h2r[tid][51] = 0.f;
    __syncthreads();

    if (tid < VOCAB) {
        float wr[51];
        #pragma unroll
        for (int k = 0; k < 51; k++) wr[k] = wl[tid * HID + k];
        const float bv = bl[tid];
        for (int row = 0; row < CROWS; row += 2) {
            float a0 = 0.f, a1 = 0.f, c0 = 0.f, c1 = 0.f;
            const float4* hp0 = (const float4*)h2r[row];
            const float4* hp1 = (const float4*)h2r[row + 1];
            #pragma unroll
            for (int i = 0; i < 13; i++) {
                float4 h0 = hp0[i], h1 = hp1[i];
                const int k = 4 * i;
                a0 += wr[k] * h0.x;  c0 += wr[k] * h1.x;
                if (k + 1 < 51) { a1 += wr[k + 1] * h0.y; c1 += wr[k + 1] * h1.y; }
                if (k + 2 < 51) { a0 += wr[k + 2] * h0.z; c0 += wr[k + 2] * h1.z; }
                if (k + 3 < 51) { a1 += wr[k + 3] * h0.w; c1 += wr[k + 3] * h1.w; }
            }
            out[(r0 + row)     * VOCAB + tid] = a0 + a1 + bv;
            out[(r0 + row + 1) * VOCAB + tid] = c0 + c1 + bv;
        }
    }
}

extern "C" void kernel_launch(void* const* d_in, const int* in_sizes, int n_in,
                              void* d_out, int out_size, void* d_ws, size_t ws_size,
                              hipStream_t stream) {
    const int*   input = (const int*)  d_in[0];
    const float* embed = (const float*)d_in[2];
    const float* w_ih1 = (const float*)d_in[3];
    const float* w_hh1 = (const float*)d_in[4];
    const float* b1    = (const float*)d_in[5];
    const float* w_ih2 = (const float*)d_in[6];
    const float* w_hh2 = (const float*)d_in[7];
    const float* b2    = (const float*)d_in[8];
    const float* w_lin = (const float*)d_in[9];
    const float* b_lin = (const float*)d_in[10];
    float* out   = (float*)d_out;
    float* eproj = (float*)d_ws;     // 282*204*4 = 230 KB scratch

    const int n1 = VOCAB * G4;
    eproj_kernel<<<(n1 + 255) / 256, 256, 0, stream>>>(embed, w_ih1, b1, eproj);
    lstm_kernel<<<BB, 512, 0, stream>>>(input, eproj, w_hh1, w_ih2, w_hh2, b2, out);
    logits_kernel<<<(BB * TT) / CROWS, CB, 0, stream>>>(w_lin, b_lin, out);
}